// Round 9
// baseline (150.022 us; speedup 1.0000x reference)
//
#include <hip/hip_runtime.h>

// ContractExpand via bf16 MFMA — VMEM-issue-bound model, 64-row tiles:
//   out[n,b,l,:] = relu(seg_r(x)[b, l/r, :] @ W[n]^T + bias[n]) / r,  r={25,10,4,2,1}
// Halving block count halves B-fragment load instructions (each block reads
// the full 200 KB W once).  Per block (64 group-rows, 256 threads):
//   p1: batched seg-sum fp32 -> bf16 XOR-swizzled LDS [64][320]  (40 KB)
//   p2: 4 waves x (4 mtile x 5 ntile) x 10 K-steps mfma_f32_16x16x32_bf16,
//       prefetched A (LDS) / B (global bf16 W, L2-hot) frags; MFMA:VMEM = 4:1
//   p3/p4 (x2 halves): bias+relu+/r -> fp32 LDS [32][308]; coalesced float4
//       stores incl. r-repeats (LDS reused across halves)

typedef short bf16x8 __attribute__((ext_vector_type(8)));
typedef float f32x4  __attribute__((ext_vector_type(4)));

namespace {
constexpr int D    = 300;
constexpr int LSEQ = 800;
constexpr int KP   = 320;    // padded K (10 steps of 32)
constexpr int NP   = 320;    // padded N rows of Wb
constexpr int CSTR = 308;    // cout row stride (floats): 2-way alias only
constexpr int SEG_BYTES  = 64 * 640;        // 40960
constexpr int COUT_BYTES = 32 * CSTR * 4;   // 39424
constexpr int SMEM_BYTES = SEG_BYTES;       // max(40960, 39424)
}

__device__ __forceinline__ unsigned short f2bf(float f) {
  unsigned u = __float_as_uint(f);
  u += 0x7fffu + ((u >> 16) & 1u);   // RNE
  return (unsigned short)(u >> 16);
}

__global__ void convert_w(const float* __restrict__ W, short* __restrict__ Wb) {
  int idx = blockIdx.x * 256 + threadIdx.x;
  if (idx >= 5 * NP * KP) return;
  int n   = idx / (NP * KP);
  int rem = idx - n * (NP * KP);
  int c = rem / KP, k = rem - c * KP;
  float v = (c < D && k < D) ? W[(size_t)n * D * D + (size_t)c * D + k] : 0.f;
  Wb[idx] = (short)f2bf(v);
}

template<int N, int R, int G>
__device__ __forceinline__ void ce_body(const int tile, char* __restrict__ smem,
    const float* __restrict__ x, const short* __restrict__ Wb,
    const float* __restrict__ bias, float* __restrict__ out) {
  const int tid = threadIdx.x;
  const int m0  = tile * 64;                 // first group-row; M_total = 64*G
  constexpr int BQ = (R <= 5) ? R : 5;       // rows per load-batch (R % BQ == 0)

  // ---- phase 1: seg-sums, batched loads -> bf16 swizzled LDS [64][320] ----
  #pragma unroll
  for (int it = 0; it < 10; ++it) {
    const int cidx = tid + it * 256;         // 0..2559 = 64 rows x 40 chunks
    const int row  = cidx / 40;
    const int k0   = (cidx - row * 40) * 8;
    float s[8];
    #pragma unroll
    for (int j = 0; j < 8; ++j) s[j] = 0.f;
    if (k0 < D) {
      const int m   = m0 + row;
      const int bb  = m / G;
      const int grp = m - bb * G;
      const float* xp = x + ((size_t)(bb * LSEQ + grp * R)) * D + k0;
      if (k0 <= D - 8) {
        for (int qb = 0; qb < R; qb += BQ) {
          float4 a0[BQ], a1[BQ];
          #pragma unroll
          for (int j = 0; j < BQ; ++j) {
            a0[j] = *(const float4*)(xp + (size_t)(qb + j) * D);
            a1[j] = *(const float4*)(xp + (size_t)(qb + j) * D + 4);
          }
          #pragma unroll
          for (int j = 0; j < BQ; ++j) {
            s[0] += a0[j].x; s[1] += a0[j].y; s[2] += a0[j].z; s[3] += a0[j].w;
            s[4] += a1[j].x; s[5] += a1[j].y; s[6] += a1[j].z; s[7] += a1[j].w;
          }
        }
      } else {                               // k0 == 296: cols 296..299 only
        for (int qb = 0; qb < R; qb += BQ) {
          float4 a0[BQ];
          #pragma unroll
          for (int j = 0; j < BQ; ++j)
            a0[j] = *(const float4*)(xp + (size_t)(qb + j) * D);
          #pragma unroll
          for (int j = 0; j < BQ; ++j) {
            s[0] += a0[j].x; s[1] += a0[j].y; s[2] += a0[j].z; s[3] += a0[j].w;
          }
        }
      }
    }
    bf16x8 p;
    #pragma unroll
    for (int j = 0; j < 8; ++j) p[j] = (short)f2bf(s[j]);
    const int boff = (row * 640 + k0 * 2) ^ ((row & 7) << 4);
    *(bf16x8*)(smem + boff) = p;
  }
  __syncthreads();

  // ---- phase 2: MFMA, prefetched A (LDS) and B (global W) frags ----
  const int wv   = tid >> 6;
  const int lane = tid & 63;
  const int cr   = lane & 15;    // A row / B col / C col
  const int kh   = lane >> 4;    // k-half; C row = kh*4 + reg

  f32x4 acc[4][5];
  #pragma unroll
  for (int mt = 0; mt < 4; ++mt)
    #pragma unroll
    for (int t = 0; t < 5; ++t) acc[mt][t] = (f32x4){0.f, 0.f, 0.f, 0.f};

  const short* __restrict__ Wn = Wb + (size_t)N * NP * KP;
  const short* __restrict__ wp[5];
  #pragma unroll
  for (int t = 0; t < 5; ++t)
    wp[t] = Wn + (size_t)((wv * 5 + t) * 16 + cr) * KP + kh * 8;

  const int swz = (cr & 7) << 4;             // rows mt*16+cr all ≡ cr (mod 8)
  int abase[4];
  #pragma unroll
  for (int mt = 0; mt < 4; ++mt) abase[mt] = (mt * 16 + cr) * 640 + kh * 16;

  bf16x8 bpre[5], apre[4];
  #pragma unroll
  for (int t = 0; t < 5; ++t) bpre[t] = *(const bf16x8*)(wp[t]);
  #pragma unroll
  for (int mt = 0; mt < 4; ++mt)
    apre[mt] = *(const bf16x8*)(smem + (abase[mt] ^ swz));

  #pragma unroll
  for (int ks = 0; ks < 10; ++ks) {
    bf16x8 bcur[5], acur[4];
    #pragma unroll
    for (int t = 0; t < 5; ++t) bcur[t] = bpre[t];
    #pragma unroll
    for (int mt = 0; mt < 4; ++mt) acur[mt] = apre[mt];
    if (ks < 9) {                            // prefetch ks+1 while MFMAs run
      #pragma unroll
      for (int t = 0; t < 5; ++t) bpre[t] = *(const bf16x8*)(wp[t] + (ks + 1) * 32);
      #pragma unroll
      for (int mt = 0; mt < 4; ++mt)
        apre[mt] = *(const bf16x8*)(smem + ((abase[mt] + (ks + 1) * 64) ^ swz));
    }
    #pragma unroll
    for (int t = 0; t < 5; ++t)
      #pragma unroll
      for (int mt = 0; mt < 4; ++mt)
        acc[mt][t] = __builtin_amdgcn_mfma_f32_16x16x32_bf16(acur[mt], bcur[t], acc[mt][t], 0, 0, 0);
  }
  __syncthreads();                           // seg reads done; LDS reused for cout

  // ---- phases 3+4, two 32-row halves sharing the cout LDS ----
  float* __restrict__ cout = (float*)smem;
  const float inv_r = 1.0f / (float)R;
  #pragma unroll
  for (int half = 0; half < 2; ++half) {
    // p3: bias + relu + /R -> fp32 LDS [32][CSTR]
    #pragma unroll
    for (int t = 0; t < 5; ++t) {
      const int col = (wv * 5 + t) * 16 + cr;
      if (col < D) {
        const float bv = bias[N * D + col];
        #pragma unroll
        for (int mt = 0; mt < 2; ++mt)
          #pragma unroll
          for (int j = 0; j < 4; ++j) {
            const int row = mt * 16 + kh * 4 + j;    // local row in this half
            cout[row * CSTR + col] =
                fmaxf(acc[half * 2 + mt][t][j] + bv, 0.f) * inv_r;
          }
      }
    }
    __syncthreads();

    // p4: coalesced float4 stores, repeats included
    constexpr int TOTAL = 32 * R * 75;
    for (int i = tid; i < TOTAL; i += 256) {
      const int rowrep = i / 75;
      const int chunk  = i - rowrep * 75;
      const int ml     = rowrep / R;
      const int q      = rowrep - ml * R;
      const int m      = m0 + half * 32 + ml;
      const int bb     = m / G;
      const int grp    = m - bb * G;
      const f32x4 v = *(const f32x4*)(cout + ml * CSTR + chunk * 4);
      float* __restrict__ op =
          out + ((size_t)((N * 64 + bb) * LSEQ) + grp * R + q) * D + chunk * 4;
      *(f32x4*)op = v;
    }
    __syncthreads();
  }
}

__global__ __launch_bounds__(256, 3)
void ce_mfma9(const float* __restrict__ x, const short* __restrict__ Wb,
              const float* __restrict__ bias, float* __restrict__ out) {
  __shared__ __align__(16) char smem[SMEM_BYTES];
  const int bid = blockIdx.x;                // scale-major, heavy-r first
  if (bid < 32)        ce_body<4, 25, 32 >(bid,        smem, x, Wb, bias, out);
  else if (bid < 112)  ce_body<3, 10, 80 >(bid - 32,   smem, x, Wb, bias, out);
  else if (bid < 312)  ce_body<2, 4, 200 >(bid - 112,  smem, x, Wb, bias, out);
  else if (bid < 712)  ce_body<1, 2, 400 >(bid - 312,  smem, x, Wb, bias, out);
  else                 ce_body<0, 1, 800 >(bid - 712,  smem, x, Wb, bias, out);
}

extern "C" void kernel_launch(void* const* d_in, const int* in_sizes, int n_in,
                              void* d_out, int out_size, void* d_ws, size_t ws_size,
                              hipStream_t stream) {
  const float* x    = (const float*)d_in[0];  // [64, 800, 300]
  const float* W    = (const float*)d_in[1];  // [5, 300, 300]
  const float* bias = (const float*)d_in[2];  // [5, 300]
  float* out        = (float*)d_out;          // [5, 64, 800, 300]
  short* Wb         = (short*)d_ws;           // [5][320][320] bf16, ~1 MB

  convert_w<<<(5 * NP * KP + 255) / 256, 256, 0, stream>>>(W, Wb);
  ce_mfma9<<<1512, 256, 0, stream>>>(x, Wb, bias, out);
}

// Round 10
// 145.463 us; speedup vs baseline: 1.0313x; 1.0313x over previous
//
#include <hip/hip_runtime.h>

// ContractExpand via bf16 MFMA — r8 structure + non-temporal output stores
// (hypothesis: 300 MB write stream thrashes per-XCD L2, forcing B/x reads to
// L3/HBM; nt stores keep W + x resident in L2).
//   out[n,b,l,:] = relu(seg_r(x)[b, l/r, :] @ W[n]^T + bias[n]) / r,  r={25,10,4,2,1}
// Per block (32 group-rows, 256 threads, 4 blocks/CU):
//   p1: batched seg-sum fp32 -> bf16 XOR-swizzled LDS [32][320]; first K-step's
//       B-frags issued before the barrier (latency hides under barrier drain)
//   p2: 4 waves x (2 mtile x 5 ntile) x 10 K-steps mfma_f32_16x16x32_bf16,
//       prefetched A (LDS) / B (global bf16 W, L2-resident) frags
//   p3: bias+relu+/r -> fp32 LDS [32][308]
//   p4: coalesced NON-TEMPORAL float4 stores incl. r-repeats

typedef short bf16x8 __attribute__((ext_vector_type(8)));
typedef float f32x4  __attribute__((ext_vector_type(4)));

namespace {
constexpr int D    = 300;
constexpr int LSEQ = 800;
constexpr int KP   = 320;    // padded K (10 steps of 32)
constexpr int NP   = 320;    // padded N rows of Wb
constexpr int CSTR = 308;    // cout row stride (floats): 2-way alias only
constexpr int SMEM_BYTES = 32 * CSTR * 4;   // 39424 >= 32*320*2 = 20480
}

__device__ __forceinline__ unsigned short f2bf(float f) {
  unsigned u = __float_as_uint(f);
  u += 0x7fffu + ((u >> 16) & 1u);   // RNE
  return (unsigned short)(u >> 16);
}

// vectorized W convert: one bf16x8 per thread-item
__global__ __launch_bounds__(256)
void convert_w(const float* __restrict__ W, short* __restrict__ Wb) {
  const int item = blockIdx.x * 256 + threadIdx.x;   // 64000 items
  if (item >= 5 * NP * KP / 8) return;
  const int off = item * 8;
  const int n   = off / (NP * KP);
  const int rem = off - n * (NP * KP);
  const int c   = rem / KP;
  const int k0  = rem - c * KP;
  float s[8];
  #pragma unroll
  for (int j = 0; j < 8; ++j) s[j] = 0.f;
  if (c < D) {
    const float* wp = W + (size_t)n * D * D + (size_t)c * D + k0;
    if (k0 < 296) {
      const float4 v0 = *(const float4*)(wp);
      const float4 v1 = *(const float4*)(wp + 4);
      s[0] = v0.x; s[1] = v0.y; s[2] = v0.z; s[3] = v0.w;
      s[4] = v1.x; s[5] = v1.y; s[6] = v1.z; s[7] = v1.w;
    } else if (k0 == 296) {
      const float4 v0 = *(const float4*)(wp);
      s[0] = v0.x; s[1] = v0.y; s[2] = v0.z; s[3] = v0.w;
    }
  }
  bf16x8 p;
  #pragma unroll
  for (int j = 0; j < 8; ++j) p[j] = (short)f2bf(s[j]);
  *(bf16x8*)(Wb + (size_t)off) = p;
}

template<int N, int R, int G>
__device__ __forceinline__ void ce_body(const int tile, char* __restrict__ smem,
    const float* __restrict__ x, const short* __restrict__ Wb,
    const float* __restrict__ bias, float* __restrict__ out) {
  const int tid = threadIdx.x;
  const int m0  = tile * 32;                 // first group-row; M_total = 64*G
  constexpr int BQ = (R <= 5) ? R : 5;       // rows per load-batch (R % BQ == 0)

  // ---- phase 1: seg-sums, batched loads -> bf16 swizzled LDS [32][320] ----
  #pragma unroll
  for (int it = 0; it < 5; ++it) {
    const int cidx = tid + it * 256;         // 0..1279 = 32 rows x 40 chunks
    const int row  = cidx / 40;
    const int k0   = (cidx - row * 40) * 8;
    float s[8];
    #pragma unroll
    for (int j = 0; j < 8; ++j) s[j] = 0.f;
    if (k0 < D) {
      const int m   = m0 + row;
      const int bb  = m / G;
      const int grp = m - bb * G;
      const float* xp = x + ((size_t)(bb * LSEQ + grp * R)) * D + k0;
      if (k0 <= D - 8) {
        for (int qb = 0; qb < R; qb += BQ) {
          float4 a0[BQ], a1[BQ];
          #pragma unroll
          for (int j = 0; j < BQ; ++j) {
            a0[j] = *(const float4*)(xp + (size_t)(qb + j) * D);
            a1[j] = *(const float4*)(xp + (size_t)(qb + j) * D + 4);
          }
          #pragma unroll
          for (int j = 0; j < BQ; ++j) {
            s[0] += a0[j].x; s[1] += a0[j].y; s[2] += a0[j].z; s[3] += a0[j].w;
            s[4] += a1[j].x; s[5] += a1[j].y; s[6] += a1[j].z; s[7] += a1[j].w;
          }
        }
      } else {                               // k0 == 296: cols 296..299 only
        for (int qb = 0; qb < R; qb += BQ) {
          float4 a0[BQ];
          #pragma unroll
          for (int j = 0; j < BQ; ++j)
            a0[j] = *(const float4*)(xp + (size_t)(qb + j) * D);
          #pragma unroll
          for (int j = 0; j < BQ; ++j) {
            s[0] += a0[j].x; s[1] += a0[j].y; s[2] += a0[j].z; s[3] += a0[j].w;
          }
        }
      }
    }
    bf16x8 p;
    #pragma unroll
    for (int j = 0; j < 8; ++j) p[j] = (short)f2bf(s[j]);
    const int boff = (row * 640 + k0 * 2) ^ ((row & 7) << 4);
    *(bf16x8*)(smem + boff) = p;
  }

  // issue first B-frag loads BEFORE the barrier: latency hides under drain
  const int wv   = tid >> 6;
  const int lane = tid & 63;
  const int cr   = lane & 15;    // A row / B col / C col
  const int kh   = lane >> 4;    // k-half; C row = kh*4 + reg

  const short* __restrict__ Wn = Wb + (size_t)N * NP * KP;
  const short* __restrict__ wp[5];
  #pragma unroll
  for (int t = 0; t < 5; ++t)
    wp[t] = Wn + (size_t)((wv * 5 + t) * 16 + cr) * KP + kh * 8;

  bf16x8 bpre[5];
  #pragma unroll
  for (int t = 0; t < 5; ++t) bpre[t] = *(const bf16x8*)(wp[t]);

  __syncthreads();

  // ---- phase 2: MFMA, prefetched A (LDS) and B (global W) frags ----
  f32x4 acc[2][5];
  #pragma unroll
  for (int mt = 0; mt < 2; ++mt)
    #pragma unroll
    for (int t = 0; t < 5; ++t) acc[mt][t] = (f32x4){0.f, 0.f, 0.f, 0.f};

  const int swz0 = (cr & 7) << 4;            // same key for rows cr and 16+cr
  const int abase0 = cr * 640        + kh * 16;
  const int abase1 = (16 + cr) * 640 + kh * 16;

  bf16x8 a0pre = *(const bf16x8*)(smem + (abase0 ^ swz0));
  bf16x8 a1pre = *(const bf16x8*)(smem + (abase1 ^ swz0));

  #pragma unroll
  for (int ks = 0; ks < 10; ++ks) {
    bf16x8 bcur[5];
    #pragma unroll
    for (int t = 0; t < 5; ++t) bcur[t] = bpre[t];
    const bf16x8 a0 = a0pre, a1 = a1pre;
    if (ks < 9) {                            // prefetch ks+1 while MFMAs run
      #pragma unroll
      for (int t = 0; t < 5; ++t) bpre[t] = *(const bf16x8*)(wp[t] + (ks + 1) * 32);
      a0pre = *(const bf16x8*)(smem + ((abase0 + (ks + 1) * 64) ^ swz0));
      a1pre = *(const bf16x8*)(smem + ((abase1 + (ks + 1) * 64) ^ swz0));
    }
    #pragma unroll
    for (int t = 0; t < 5; ++t) {
      acc[0][t] = __builtin_amdgcn_mfma_f32_16x16x32_bf16(a0, bcur[t], acc[0][t], 0, 0, 0);
      acc[1][t] = __builtin_amdgcn_mfma_f32_16x16x32_bf16(a1, bcur[t], acc[1][t], 0, 0, 0);
    }
  }
  __syncthreads();                           // seg reads done; LDS reused for cout

  // ---- phase 3: bias + relu + /R -> fp32 LDS tile [32][CSTR] ----
  float* __restrict__ cout = (float*)smem;
  const float inv_r = 1.0f / (float)R;
  #pragma unroll
  for (int t = 0; t < 5; ++t) {
    const int col = (wv * 5 + t) * 16 + cr;
    if (col < D) {
      const float bv = bias[N * D + col];
      #pragma unroll
      for (int mt = 0; mt < 2; ++mt)
        #pragma unroll
        for (int j = 0; j < 4; ++j) {
          const int row = mt * 16 + kh * 4 + j;
          cout[row * CSTR + col] = fmaxf(acc[mt][t][j] + bv, 0.f) * inv_r;
        }
    }
  }
  __syncthreads();

  // ---- phase 4: coalesced NON-TEMPORAL float4 stores, repeats included ----
  constexpr int TOTAL = 32 * R * 75;         // (group-rows x repeats) x float4-chunks
  for (int i = tid; i < TOTAL; i += 256) {
    const int rowrep = i / 75;
    const int chunk  = i - rowrep * 75;
    const int ml     = rowrep / R;
    const int q      = rowrep - ml * R;
    const int m      = m0 + ml;
    const int bb     = m / G;
    const int grp    = m - bb * G;
    const f32x4 v = *(const f32x4*)(cout + ml * CSTR + chunk * 4);
    float* __restrict__ op =
        out + ((size_t)((N * 64 + bb) * LSEQ) + grp * R + q) * D + chunk * 4;
    __builtin_nontemporal_store(v, (f32x4*)op);
  }
}

__global__ __launch_bounds__(256, 4)
void ce_mfma10(const float* __restrict__ x, const short* __restrict__ Wb,
               const float* __restrict__ bias, float* __restrict__ out) {
  __shared__ __align__(16) char smem[SMEM_BYTES];
  const int bid = blockIdx.x;                // scale-major, heavy-r first
  if (bid < 64)        ce_body<4, 25, 32 >(bid,        smem, x, Wb, bias, out);
  else if (bid < 224)  ce_body<3, 10, 80 >(bid - 64,   smem, x, Wb, bias, out);
  else if (bid < 624)  ce_body<2, 4, 200 >(bid - 224,  smem, x, Wb, bias, out);
  else if (bid < 1424) ce_body<1, 2, 400 >(bid - 624,  smem, x, Wb, bias, out);
  else                 ce_body<0, 1, 800 >(bid - 1424, smem, x, Wb, bias, out);
}

extern "C" void kernel_launch(void* const* d_in, const int* in_sizes, int n_in,
                              void* d_out, int out_size, void* d_ws, size_t ws_size,
                              hipStream_t stream) {
  const float* x    = (const float*)d_in[0];  // [64, 800, 300]
  const float* W    = (const float*)d_in[1];  // [5, 300, 300]
  const float* bias = (const float*)d_in[2];  // [5, 300]
  float* out        = (float*)d_out;          // [5, 64, 800, 300]
  short* Wb         = (short*)d_ws;           // [5][320][320] bf16, ~1 MB

  convert_w<<<250, 256, 0, stream>>>(W, Wb);
  ce_mfma10<<<3024, 256, 0, stream>>>(x, Wb, bias, out);
}